// Round 1
// baseline (419.863 us; speedup 1.0000x reference)
//
#include <hip/hip_runtime.h>
#include <hip/hip_bf16.h>
#include <math.h>

#define NA 5000
#define NE 100000
#define F 128
#define KB 16
#define RCUT 5.0f

typedef long long i64;

__device__ __forceinline__ float swish_f(float t, float a, float b){
    return a * t / (1.0f + __expf(-b * t));
}

// ---------------------------------------------------------------------------
// Generic fused linear stage: out[c,n,i] = post( addx?[n,i] + b[c,i] +
//     sum_j W[c,i,j] * pre(in[c,n,j]) )
// pre  = swish(sw_a[IN_SW], sw_b[IN_SW]) if IN_SW >= 0
// post = swish(sw_a[OUT_SW], sw_b[OUT_SW]) if OUT_SW >= 0
// Block: 256 threads = 32 atoms x 128 features, 4x4 register micro-tile.
// ---------------------------------------------------------------------------
template<int IN_SW, int ADD_X, int OUT_SW>
__global__ __launch_bounds__(256)
void lin_kernel(const float* __restrict__ in, i64 in_cstride,
                const float* __restrict__ W, const float* __restrict__ bias,
                const float* __restrict__ addx,
                float* __restrict__ out,
                const float* __restrict__ sw_a, const float* __restrict__ sw_b,
                int n)
{
    __shared__ float lin_s[32][128];
    const int c = blockIdx.y;
    const int a0 = blockIdx.x * 32;
    const int tid = threadIdx.x;

    float ina = 0.f, inb = 0.f;
    if (IN_SW >= 0){ ina = sw_a[IN_SW]; inb = sw_b[IN_SW]; }
    const float* inc = in + (i64)c * in_cstride;

    #pragma unroll
    for (int it = 0; it < 4; ++it){
        int idx = tid + it * 256;       // 0..1023 float4 slots
        int a  = idx >> 5;              // 0..31 atom in tile
        int j4 = idx & 31;              // 0..31 float4 along features
        int nn = a0 + a;
        float4 v = make_float4(0.f, 0.f, 0.f, 0.f);
        if (nn < n) v = *(const float4*)(inc + (i64)nn * F + j4 * 4);
        if (IN_SW >= 0){
            v.x = swish_f(v.x, ina, inb);
            v.y = swish_f(v.y, ina, inb);
            v.z = swish_f(v.z, ina, inb);
            v.w = swish_f(v.w, ina, inb);
        }
        *(float4*)(&lin_s[a][j4 * 4]) = v;
    }
    __syncthreads();

    const int fg = tid & 31;   // feature group: features fg*4 .. fg*4+3
    const int ag = tid >> 5;   // atom group:    atoms   ag*4 .. ag*4+3
    float acc[4][4];
    #pragma unroll
    for (int a = 0; a < 4; ++a)
        #pragma unroll
        for (int f = 0; f < 4; ++f) acc[a][f] = 0.f;

    const float* Wc = W + (i64)c * F * F;
    #pragma unroll 4
    for (int j4 = 0; j4 < 32; ++j4){
        float4 iv[4];
        #pragma unroll
        for (int a = 0; a < 4; ++a) iv[a] = *(const float4*)(&lin_s[ag * 4 + a][j4 * 4]);
        #pragma unroll
        for (int f = 0; f < 4; ++f){
            float4 wv = *(const float4*)(Wc + (i64)(fg * 4 + f) * F + j4 * 4);
            #pragma unroll
            for (int a = 0; a < 4; ++a){
                acc[a][f] += iv[a].x * wv.x;
                acc[a][f] += iv[a].y * wv.y;
                acc[a][f] += iv[a].z * wv.z;
                acc[a][f] += iv[a].w * wv.w;
            }
        }
    }

    float oa = 0.f, ob = 0.f;
    if (OUT_SW >= 0){ oa = sw_a[OUT_SW]; ob = sw_b[OUT_SW]; }
    float4 bv = *(const float4*)(bias + c * F + fg * 4);

    #pragma unroll
    for (int a = 0; a < 4; ++a){
        int nn = a0 + ag * 4 + a;
        if (nn >= n) continue;
        float4 o;
        o.x = acc[a][0] + bv.x;
        o.y = acc[a][1] + bv.y;
        o.z = acc[a][2] + bv.z;
        o.w = acc[a][3] + bv.w;
        if (ADD_X){
            float4 xv = *(const float4*)(addx + (i64)nn * F + fg * 4);
            o.x += xv.x; o.y += xv.y; o.z += xv.z; o.w += xv.w;
        }
        if (OUT_SW >= 0){
            o.x = swish_f(o.x, oa, ob);
            o.y = swish_f(o.y, oa, ob);
            o.z = swish_f(o.z, oa, ob);
            o.w = swish_f(o.w, oa, ob);
        }
        *(float4*)(out + (i64)c * n * F + (i64)nn * F + fg * 4) = o;
    }
}

// ---------------------------------------------------------------------------
// CSR build: histogram -> block scan -> scatter
// ---------------------------------------------------------------------------
__global__ void hist_kernel(const int* __restrict__ nbrs, int* __restrict__ cnt){
    int e = blockIdx.x * 256 + threadIdx.x;
    if (e < NE) atomicAdd(&cnt[nbrs[2 * e]], 1);
}

__global__ __launch_bounds__(1024)
void scan_kernel(const int* __restrict__ cnt, int* __restrict__ offs){
    __shared__ int part[1024];
    int t = threadIdx.x;
    int loc[5]; int s = 0;
    #pragma unroll
    for (int c = 0; c < 5; ++c){
        int i = t * 5 + c;
        int v = (i < NA) ? cnt[i] : 0;
        loc[c] = s; s += v;
    }
    part[t] = s;
    __syncthreads();
    for (int off = 1; off < 1024; off <<= 1){
        int v = (t >= off) ? part[t - off] : 0;
        __syncthreads();
        part[t] += v;
        __syncthreads();
    }
    int bs = (t == 0) ? 0 : part[t - 1];
    #pragma unroll
    for (int c = 0; c < 5; ++c){
        int i = t * 5 + c;
        if (i <= NA) offs[i] = bs + loc[c];
    }
}

__global__ void scatter_kernel(const int* __restrict__ nbrs, const int* __restrict__ offs,
                               int* __restrict__ fill, int* __restrict__ elist){
    int e = blockIdx.x * 256 + threadIdx.x;
    if (e < NE){
        int i0 = nbrs[2 * e];
        int p = atomicAdd(&fill[i0], 1);
        elist[offs[i0] + p] = e;
    }
}

// ---------------------------------------------------------------------------
// Bernstein basis dot:  sum_k G[k] * C(15,k) e^k (1-e)^(15-k),  e = exp(-g r)
// ---------------------------------------------------------------------------
__device__ __forceinline__ float bern_dot(float r, float g, const float* __restrict__ G){
    float e = __expf(-g * r);
    float one = 1.0f - e;
    float b[KB];
    const float C[KB] = {1.f, 15.f, 105.f, 455.f, 1365.f, 3003.f, 5005.f, 6435.f,
                         6435.f, 5005.f, 3003.f, 1365.f, 455.f, 105.f, 15.f, 1.f};
    float ep = 1.f;
    #pragma unroll
    for (int k = 0; k < KB; ++k){ b[k] = C[k] * ep; ep *= e; }
    float op = 1.f;
    #pragma unroll
    for (int k = KB - 1; k >= 0; --k){ b[k] *= op; op *= one; }
    float s = 0.f;
    #pragma unroll
    for (int k = 0; k < KB; ++k) s += G[k] * b[k];
    return s;
}

// ---------------------------------------------------------------------------
// Per-atom q accumulation + P/D bilinear inner products + assemble inp.
// Block = 128 threads (one per feature), grid = NA atoms.
// ---------------------------------------------------------------------------
__global__ __launch_bounds__(128)
void q_kernel(const float* __restrict__ xyz, const int* __restrict__ nbrs,
              const int* __restrict__ offs, const int* __restrict__ elist,
              const float* __restrict__ res,   // 4 x NA x F
              const float* __restrict__ Gs, const float* __restrict__ Gp, const float* __restrict__ Gd,
              const float* __restrict__ gs_p, const float* __restrict__ gp_p, const float* __restrict__ gd_p,
              const float* __restrict__ P1, const float* __restrict__ P2,
              const float* __restrict__ D1, const float* __restrict__ D2,
              float* __restrict__ inp)
{
    const int n = blockIdx.x;
    const int f = threadIdx.x;

    float G0[KB], G1[KB], G2[KB];
    #pragma unroll
    for (int q4 = 0; q4 < 4; ++q4){
        *(float4*)(&G0[q4 * 4]) = *(const float4*)(Gs + f * KB + q4 * 4);
        *(float4*)(&G1[q4 * 4]) = *(const float4*)(Gp + f * KB + q4 * 4);
        *(float4*)(&G2[q4 * 4]) = *(const float4*)(Gd + f * KB + q4 * 4);
    }
    const float gamma0 = fmaxf(gs_p[0], 0.f);
    const float gamma1 = fmaxf(gp_p[0], 0.f);
    const float gamma2 = fmaxf(gd_p[0], 0.f);

    const float* res1 = res + (i64)NA * F;
    const float* res2 = res + 2 * (i64)NA * F;
    const float* res3 = res + 3 * (i64)NA * F;

    const float xn0 = xyz[3 * n], xn1 = xyz[3 * n + 1], xn2 = xyz[3 * n + 2];
    float qs = 0.f;
    float qp0 = 0.f, qp1 = 0.f, qp2 = 0.f;
    float qd0 = 0.f, qd1 = 0.f, qd2 = 0.f, qd3 = 0.f, qd4 = 0.f;

    const int e0 = offs[n], e1 = offs[n + 1];
    for (int ee = e0; ee < e1; ++ee){
        int e = elist[ee];
        int i1 = nbrs[2 * e + 1];
        float dx = xyz[3 * i1]     - xn0;
        float dy = xyz[3 * i1 + 1] - xn1;
        float dz = xyz[3 * i1 + 2] - xn2;
        float r2 = dx * dx + dy * dy + dz * dz + 3e-15f;
        float r = sqrtf(r2);
        if (r >= RCUT) continue;             // fcut == 0 -> zero contribution
        float fcut = __expf(-r2 / ((RCUT - r) * (RCUT + r)));

        float cs = bern_dot(r, gamma0, G0) * fcut;
        float cp = bern_dot(r, gamma1, G1) * fcut;
        float cd = bern_dot(r, gamma2, G2) * fcut;

        float ir  = 1.0f / r;
        float ir2 = ir * ir;
        const float s3 = 1.7320508075688772f;
        float y10 = dy * ir, y11 = dz * ir, y12 = dx * ir;
        float y20 = s3 * dx * dy * ir2;
        float y21 = s3 * dy * dz * ir2;
        float y22 = (1.5f * dz * dz - 0.5f * r2) * ir2;
        float y23 = s3 * dx * dz * ir2;
        float y24 = 0.5f * s3 * (dx * dx - dy * dy) * ir2;

        float a1 = res1[(i64)i1 * F + f];
        float a2 = res2[(i64)i1 * F + f];
        float a3 = res3[(i64)i1 * F + f];

        qs += a1 * cs;
        float tp = a2 * cp;
        qp0 += tp * y10; qp1 += tp * y11; qp2 += tp * y12;
        float td = a3 * cd;
        qd0 += td * y20; qd1 += td * y21; qd2 += td * y22; qd3 += td * y23; qd4 += td * y24;
    }

    __shared__ float qpT[3][128];
    __shared__ float qdT[5][128];
    qpT[0][f] = qp0; qpT[1][f] = qp1; qpT[2][f] = qp2;
    qdT[0][f] = qd0; qdT[1][f] = qd1; qdT[2][f] = qd2; qdT[3][f] = qd3; qdT[4][f] = qd4;
    __syncthreads();

    float t1[3] = {0.f, 0.f, 0.f}, t2[3] = {0.f, 0.f, 0.f};
    float u1[5] = {0.f, 0.f, 0.f, 0.f, 0.f}, u2[5] = {0.f, 0.f, 0.f, 0.f, 0.f};
    const float* P1r = P1 + f * F;
    const float* P2r = P2 + f * F;
    const float* D1r = D1 + f * F;
    const float* D2r = D2 + f * F;

    #pragma unroll 2
    for (int j4 = 0; j4 < 32; ++j4){
        float4 p1 = *(const float4*)(P1r + j4 * 4);
        float4 p2 = *(const float4*)(P2r + j4 * 4);
        #pragma unroll
        for (int m = 0; m < 3; ++m){
            float4 q = *(const float4*)(&qpT[m][j4 * 4]);
            t1[m] += p1.x * q.x + p1.y * q.y + p1.z * q.z + p1.w * q.w;
            t2[m] += p2.x * q.x + p2.y * q.y + p2.z * q.z + p2.w * q.w;
        }
        float4 d1 = *(const float4*)(D1r + j4 * 4);
        float4 d2 = *(const float4*)(D2r + j4 * 4);
        #pragma unroll
        for (int m = 0; m < 5; ++m){
            float4 q = *(const float4*)(&qdT[m][j4 * 4]);
            u1[m] += d1.x * q.x + d1.y * q.y + d1.z * q.z + d1.w * q.w;
            u2[m] += d2.x * q.x + d2.y * q.y + d2.z * q.z + d2.w * q.w;
        }
    }

    float s = 0.f;
    #pragma unroll
    for (int m = 0; m < 3; ++m) s += t1[m] * t2[m];
    #pragma unroll
    for (int m = 0; m < 5; ++m) s += u1[m] * u2[m];

    inp[(i64)n * F + f] = res[(i64)n * F + f] + qs + s;
}

// ---------------------------------------------------------------------------
extern "C" void kernel_launch(void* const* d_in, const int* in_sizes, int n_in,
                              void* d_out, int out_size, void* d_ws, size_t ws_size,
                              hipStream_t stream)
{
    const float* xyz     = (const float*)d_in[0];
    const float* x_tilde = (const float*)d_in[1];
    const int*   nbrs    = (const int*)d_in[2];
    const float* rm_W1 = (const float*)d_in[3],  *rm_b1 = (const float*)d_in[4];
    const float* rm_W2 = (const float*)d_in[5],  *rm_b2 = (const float*)d_in[6];
    const float* rm_W3 = (const float*)d_in[7],  *rm_b3 = (const float*)d_in[8];
    const float* rl_W1 = (const float*)d_in[9],  *rl_b1 = (const float*)d_in[10];
    const float* rl_W2 = (const float*)d_in[11], *rl_b2 = (const float*)d_in[12];
    const float* rl_W3 = (const float*)d_in[13], *rl_b3 = (const float*)d_in[14];
    const float* G_s = (const float*)d_in[15], *G_p = (const float*)d_in[16], *G_d = (const float*)d_in[17];
    const float* P_1 = (const float*)d_in[18], *P_2 = (const float*)d_in[19];
    const float* D_1 = (const float*)d_in[20], *D_2 = (const float*)d_in[21];
    const float* gamma_s = (const float*)d_in[22], *gamma_p = (const float*)d_in[23], *gamma_d = (const float*)d_in[24];
    const float* sw_a = (const float*)d_in[25], *sw_b = (const float*)d_in[26];

    const i64 S = (i64)NA * F;
    float* buf0 = (float*)d_ws;        // 4S floats
    float* buf1 = buf0 + 4 * S;        // 4S floats
    float* res  = buf0 + 8 * S;        // 4S floats
    int* cnt   = (int*)(buf0 + 12 * S);
    int* fill  = cnt + NA;
    int* offs  = fill + NA;
    int* elist = offs + NA + 8;

    hipMemsetAsync(cnt, 0, 2 * NA * sizeof(int), stream);

    dim3 blk(256);
    dim3 g4((NA + 31) / 32, 4), g1((NA + 31) / 32, 1);

    // residual MLP (4 channels)
    lin_kernel<0, 0, 1><<<g4, blk, 0, stream>>>(x_tilde, 0, rm_W1, rm_b1, nullptr, buf0, sw_a, sw_b, NA);
    lin_kernel<-1, 1, 2><<<g4, blk, 0, stream>>>(buf0, S, rm_W2, rm_b2, x_tilde, buf1, sw_a, sw_b, NA);
    lin_kernel<-1, 1, -1><<<g4, blk, 0, stream>>>(buf1, S, rm_W3, rm_b3, x_tilde, res, sw_a, sw_b, NA);

    // CSR build
    hist_kernel<<<(NE + 255) / 256, 256, 0, stream>>>(nbrs, cnt);
    scan_kernel<<<1, 1024, 0, stream>>>(cnt, offs);
    scatter_kernel<<<(NE + 255) / 256, 256, 0, stream>>>(nbrs, offs, fill, elist);

    // per-atom moments + bilinear contraction -> inp (into buf0)
    q_kernel<<<NA, 128, 0, stream>>>(xyz, nbrs, offs, elist, res, G_s, G_p, G_d,
                                     gamma_s, gamma_p, gamma_d, P_1, P_2, D_1, D_2, buf0);

    // final MLP
    lin_kernel<3, 0, 4><<<g1, blk, 0, stream>>>(buf0, 0, rl_W1, rl_b1, nullptr, buf1, sw_a, sw_b, NA);
    lin_kernel<-1, 1, 5><<<g1, blk, 0, stream>>>(buf1, 0, rl_W2, rl_b2, buf0, res, sw_a, sw_b, NA);
    lin_kernel<-1, 0, -1><<<g1, blk, 0, stream>>>(res, 0, rl_W3, rl_b3, nullptr, (float*)d_out, sw_a, sw_b, NA);
}

// Round 2
// 274.060 us; speedup vs baseline: 1.5320x; 1.5320x over previous
//
#include <hip/hip_runtime.h>
#include <hip/hip_bf16.h>
#include <math.h>

#define NA 5000
#define NE 100000
#define F 128
#define KB 16
#define RCUT 5.0f
#define RECW 28   // words per edge record: i1, ux,uy,uz, 24 bf16-pair words

typedef long long i64;

__device__ __forceinline__ float swish_f(float t, float a, float b){
    return a * t / (1.0f + __expf(-b * t));
}
__device__ __forceinline__ float bf2f(unsigned short u){
    return __uint_as_float(((unsigned)u) << 16);
}
__device__ __forceinline__ unsigned short f2bf(float x){
    unsigned b = __float_as_uint(x);
    return (unsigned short)((b + 0x8000u) >> 16);
}
__device__ __forceinline__ unsigned pack2(float a, float b){
    return (unsigned)f2bf(a) | ((unsigned)f2bf(b) << 16);
}

// ---------------------------------------------------------------------------
// Shared tiled-GEMM core: C[32 atoms][128 f] += W(128x128) * As(K-major in LDS)
// 256 threads: fg = tid&31 (4 feats), ag = tid>>5 (4 atoms) -> 4x4 micro-tile.
// W streamed from global ONCE per block via transposed LDS panels (K-major).
// ---------------------------------------------------------------------------
__device__ __forceinline__ void gemm128(const float (*As)[132], float (*Wp)[128],
                                        const float* __restrict__ Wg,
                                        float acc[4][4], int fg, int ag, int wi, int wc)
{
    for (int jp = 0; jp < 4; ++jp){
        // stage transposed W panel: W[i][jp*32+wc*16+q] -> Wp[wc*16+q][i]
        #pragma unroll
        for (int k = 0; k < 4; ++k){
            float4 v = *(const float4*)(Wg + (i64)wi * F + jp * 32 + wc * 16 + k * 4);
            Wp[wc*16 + k*4 + 0][wi] = v.x;
            Wp[wc*16 + k*4 + 1][wi] = v.y;
            Wp[wc*16 + k*4 + 2][wi] = v.z;
            Wp[wc*16 + k*4 + 3][wi] = v.w;
        }
        __syncthreads();
        #pragma unroll
        for (int jj = 0; jj < 8; ++jj){
            float4 av[4], wv[4];
            #pragma unroll
            for (int aa = 0; aa < 4; ++aa) av[aa] = *(const float4*)&As[ag*4 + aa][jp*32 + jj*4];
            #pragma unroll
            for (int d = 0; d < 4; ++d) wv[d] = *(const float4*)&Wp[jj*4 + d][fg*4];
            #pragma unroll
            for (int aa = 0; aa < 4; ++aa){
                acc[aa][0] += av[aa].x*wv[0].x + av[aa].y*wv[1].x + av[aa].z*wv[2].x + av[aa].w*wv[3].x;
                acc[aa][1] += av[aa].x*wv[0].y + av[aa].y*wv[1].y + av[aa].z*wv[2].y + av[aa].w*wv[3].y;
                acc[aa][2] += av[aa].x*wv[0].z + av[aa].y*wv[1].z + av[aa].z*wv[2].z + av[aa].w*wv[3].z;
                acc[aa][3] += av[aa].x*wv[0].w + av[aa].y*wv[1].w + av[aa].z*wv[2].w + av[aa].w*wv[3].w;
            }
        }
        __syncthreads();
    }
}

// ---------------------------------------------------------------------------
// Fused 3-stage MLP: one launch replaces 3 lin stages.
//  act0 = sw_{S0}(x); z1 = W1 act0 + b1; act1 = sw_{S1}(z1);
//  z2 = W2 act1 + b2 + (ADD2? x); act2 = sw_{S2}(z2);
//  z3 = W3 act2 + b3 + (ADD3? x)  -> out
// ---------------------------------------------------------------------------
template<int S0,int S1,int S2,int ADD2,int ADD3>
__global__ __launch_bounds__(256)
void mlp3_kernel(const float* __restrict__ in,
                 const float* __restrict__ W1, const float* __restrict__ b1,
                 const float* __restrict__ W2, const float* __restrict__ b2,
                 const float* __restrict__ W3, const float* __restrict__ b3,
                 float* __restrict__ out, i64 out_cstride,
                 const float* __restrict__ sw_a, const float* __restrict__ sw_b,
                 int n)
{
    __shared__ float As[32][132];
    __shared__ float Wp[32][128];
    const int tid = threadIdx.x;
    const int c = blockIdx.y;
    const int a0 = blockIdx.x * 32;
    const int fg = tid & 31, ag = tid >> 5;
    const int wi = tid >> 1, wc = tid & 1;

    const float* Wc1 = W1 + (i64)c * F * F; const float* bc1 = b1 + c * F;
    const float* Wc2 = W2 + (i64)c * F * F; const float* bc2 = b2 + c * F;
    const float* Wc3 = W3 + (i64)c * F * F; const float* bc3 = b3 + c * F;

    // stage input (with swish S0)
    {
        int a = tid >> 3, seg = tid & 7;
        int nn = a0 + a;
        float aS = sw_a[S0], bS = sw_b[S0];
        #pragma unroll
        for (int k = 0; k < 4; ++k){
            float4 v = make_float4(0.f,0.f,0.f,0.f);
            if (nn < n) v = *(const float4*)(in + (i64)nn * F + seg*16 + k*4);
            v.x = swish_f(v.x, aS, bS); v.y = swish_f(v.y, aS, bS);
            v.z = swish_f(v.z, aS, bS); v.w = swish_f(v.w, aS, bS);
            *(float4*)&As[a][seg*16 + k*4] = v;
        }
    }
    __syncthreads();

    float acc[4][4];
    #pragma unroll
    for (int aa=0;aa<4;++aa) { acc[aa][0]=acc[aa][1]=acc[aa][2]=acc[aa][3]=0.f; }
    gemm128(As, Wp, Wc1, acc, fg, ag, wi, wc);

    { // epilogue 1 -> As
        float aS = sw_a[S1], bS = sw_b[S1];
        float4 bv = *(const float4*)(bc1 + fg*4);
        #pragma unroll
        for (int aa=0;aa<4;++aa){
            float4 o;
            o.x = swish_f(acc[aa][0] + bv.x, aS, bS);
            o.y = swish_f(acc[aa][1] + bv.y, aS, bS);
            o.z = swish_f(acc[aa][2] + bv.z, aS, bS);
            o.w = swish_f(acc[aa][3] + bv.w, aS, bS);
            *(float4*)&As[ag*4 + aa][fg*4] = o;
        }
    }
    __syncthreads();

    #pragma unroll
    for (int aa=0;aa<4;++aa) { acc[aa][0]=acc[aa][1]=acc[aa][2]=acc[aa][3]=0.f; }
    gemm128(As, Wp, Wc2, acc, fg, ag, wi, wc);

    { // epilogue 2 -> As
        float aS = sw_a[S2], bS = sw_b[S2];
        float4 bv = *(const float4*)(bc2 + fg*4);
        #pragma unroll
        for (int aa=0;aa<4;++aa){
            int nn = a0 + ag*4 + aa;
            float4 xv = make_float4(0.f,0.f,0.f,0.f);
            if (ADD2 && nn < n) xv = *(const float4*)(in + (i64)nn * F + fg*4);
            float4 o;
            o.x = swish_f(acc[aa][0] + bv.x + xv.x, aS, bS);
            o.y = swish_f(acc[aa][1] + bv.y + xv.y, aS, bS);
            o.z = swish_f(acc[aa][2] + bv.z + xv.z, aS, bS);
            o.w = swish_f(acc[aa][3] + bv.w + xv.w, aS, bS);
            *(float4*)&As[ag*4 + aa][fg*4] = o;
        }
    }
    __syncthreads();

    #pragma unroll
    for (int aa=0;aa<4;++aa) { acc[aa][0]=acc[aa][1]=acc[aa][2]=acc[aa][3]=0.f; }
    gemm128(As, Wp, Wc3, acc, fg, ag, wi, wc);

    { // epilogue 3 -> global
        float4 bv = *(const float4*)(bc3 + fg*4);
        #pragma unroll
        for (int aa=0;aa<4;++aa){
            int nn = a0 + ag*4 + aa;
            if (nn >= n) continue;
            float4 xv = make_float4(0.f,0.f,0.f,0.f);
            if (ADD3) xv = *(const float4*)(in + (i64)nn * F + fg*4);
            float4 o;
            o.x = acc[aa][0] + bv.x + xv.x;
            o.y = acc[aa][1] + bv.y + xv.y;
            o.z = acc[aa][2] + bv.z + xv.z;
            o.w = acc[aa][3] + bv.w + xv.w;
            *(float4*)(out + (i64)c * out_cstride + (i64)nn * F + fg*4) = o;
        }
    }
}

// ---------------------------------------------------------------------------
// Edge prep: active-edge count, CSR scan, record fill
// ---------------------------------------------------------------------------
__global__ void prep_count(const float* __restrict__ xyz, const int* __restrict__ nbrs,
                           int* __restrict__ cnt){
    int e = blockIdx.x * 256 + threadIdx.x;
    if (e >= NE) return;
    int i0 = nbrs[2*e], i1 = nbrs[2*e+1];
    float dx = xyz[3*i1]   - xyz[3*i0];
    float dy = xyz[3*i1+1] - xyz[3*i0+1];
    float dz = xyz[3*i1+2] - xyz[3*i0+2];
    float r = sqrtf(dx*dx + dy*dy + dz*dz + 3e-15f);
    if (r < RCUT) atomicAdd(&cnt[i0], 1);
}

__global__ __launch_bounds__(1024)
void scan_kernel(const int* __restrict__ cnt, int* __restrict__ offs){
    __shared__ int part[1024];
    int t = threadIdx.x;
    int loc[5]; int s = 0;
    #pragma unroll
    for (int c = 0; c < 5; ++c){
        int i = t * 5 + c;
        int v = (i < NA) ? cnt[i] : 0;
        loc[c] = s; s += v;
    }
    part[t] = s;
    __syncthreads();
    for (int off = 1; off < 1024; off <<= 1){
        int v = (t >= off) ? part[t - off] : 0;
        __syncthreads();
        part[t] += v;
        __syncthreads();
    }
    int bs = (t == 0) ? 0 : part[t - 1];
    #pragma unroll
    for (int c = 0; c < 5; ++c){
        int i = t * 5 + c;
        if (i <= NA) offs[i] = bs + loc[c];
    }
}

__device__ __forceinline__ void basis16(float r, float g, float fcut, float* b){
    const float C[KB] = {1.f,15.f,105.f,455.f,1365.f,3003.f,5005.f,6435.f,
                         6435.f,5005.f,3003.f,1365.f,455.f,105.f,15.f,1.f};
    float e = __expf(-fmaxf(g, 0.f) * r);
    float one = 1.f - e;
    float ep = 1.f;
    #pragma unroll
    for (int k = 0; k < KB; ++k){ b[k] = C[k] * ep * fcut; ep *= e; }
    float op = 1.f;
    #pragma unroll
    for (int k = KB-1; k >= 0; --k){ b[k] *= op; op *= one; }
}

__global__ void prep_fill(const float* __restrict__ xyz, const int* __restrict__ nbrs,
                          const int* __restrict__ offs, int* __restrict__ fill,
                          const float* __restrict__ gs, const float* __restrict__ gp,
                          const float* __restrict__ gd, float* __restrict__ rec){
    int e = blockIdx.x * 256 + threadIdx.x;
    if (e >= NE) return;
    int i0 = nbrs[2*e], i1 = nbrs[2*e+1];
    float dx = xyz[3*i1]   - xyz[3*i0];
    float dy = xyz[3*i1+1] - xyz[3*i0+1];
    float dz = xyz[3*i1+2] - xyz[3*i0+2];
    float r2 = dx*dx + dy*dy + dz*dz + 3e-15f;
    float r = sqrtf(r2);
    if (r >= RCUT) return;
    int pos = offs[i0] + atomicAdd(&fill[i0], 1);
    float* R = rec + (i64)pos * RECW;
    float ir = 1.f / r;
    R[0] = __int_as_float(i1);
    R[1] = dx * ir; R[2] = dy * ir; R[3] = dz * ir;
    float fcut = __expf(-r2 / ((RCUT - r) * (RCUT + r)));
    float bs[KB], bp[KB], bd[KB];
    basis16(r, gs[0], fcut, bs);
    basis16(r, gp[0], fcut, bp);
    basis16(r, gd[0], fcut, bd);
    unsigned* RW = (unsigned*)(R + 4);
    #pragma unroll
    for (int k = 0; k < 8; ++k) RW[k]      = pack2(bs[2*k], bs[2*k+1]);
    #pragma unroll
    for (int k = 0; k < 8; ++k) RW[8 + k]  = pack2(bp[2*k], bp[2*k+1]);
    #pragma unroll
    for (int k = 0; k < 8; ++k) RW[16 + k] = pack2(bd[2*k], bd[2*k+1]);
}

// ---------------------------------------------------------------------------
// Moment gather: per atom, 2 edge-slots x 128 features.
// Writes Q[m][n][f] (bf16, m=0..7: 3 p + 5 d) and inp = res0 + q_s.
// ---------------------------------------------------------------------------
__global__ __launch_bounds__(256)
void q_gather(const float* __restrict__ rec, const int* __restrict__ offs,
              const float* __restrict__ res,
              const float* __restrict__ Gs, const float* __restrict__ Gp,
              const float* __restrict__ Gd,
              float* __restrict__ inp, unsigned short* __restrict__ Q)
{
    const int n = blockIdx.x;
    const int tid = threadIdx.x;
    const int s = tid >> 7;     // slot 0/1
    const int f = tid & 127;
    const i64 S = (i64)NA * F;

    float G0[KB], G1[KB], G2[KB];
    #pragma unroll
    for (int q4 = 0; q4 < 4; ++q4){
        *(float4*)&G0[q4*4] = *(const float4*)(Gs + f*KB + q4*4);
        *(float4*)&G1[q4*4] = *(const float4*)(Gp + f*KB + q4*4);
        *(float4*)&G2[q4*4] = *(const float4*)(Gd + f*KB + q4*4);
    }

    float qs = 0.f;
    float qp0=0.f, qp1=0.f, qp2=0.f;
    float qd0=0.f, qd1=0.f, qd2=0.f, qd3=0.f, qd4=0.f;

    __shared__ float recs[16 * RECW];
    __shared__ float red[2][9][128];

    const int e0 = offs[n], e1 = offs[n+1];
    const int cnt_e = e1 - e0;
    const float s3 = 1.7320508075688772f;

    for (int base = 0; base < cnt_e; base += 16){
        int mrec = min(16, cnt_e - base);
        for (int w = tid; w < mrec * RECW; w += 256)
            recs[w] = rec[(i64)(e0 + base) * RECW + w];
        __syncthreads();
        for (int j = s; j < mrec; j += 2){
            const float* R = &recs[j * RECW];
            int i1 = __float_as_int(R[0]);
            float ux = R[1], uy = R[2], uz = R[3];
            const unsigned* bw = (const unsigned*)(R + 4);
            float ds = 0.f, dp = 0.f, dd = 0.f;
            #pragma unroll
            for (int k = 0; k < 8; ++k){
                unsigned w = bw[k];
                ds += G0[2*k] * __uint_as_float(w << 16) + G0[2*k+1] * __uint_as_float(w & 0xffff0000u);
            }
            #pragma unroll
            for (int k = 0; k < 8; ++k){
                unsigned w = bw[8+k];
                dp += G1[2*k] * __uint_as_float(w << 16) + G1[2*k+1] * __uint_as_float(w & 0xffff0000u);
            }
            #pragma unroll
            for (int k = 0; k < 8; ++k){
                unsigned w = bw[16+k];
                dd += G2[2*k] * __uint_as_float(w << 16) + G2[2*k+1] * __uint_as_float(w & 0xffff0000u);
            }
            float a1 = res[S   + (i64)i1*F + f];
            float a2 = res[2*S + (i64)i1*F + f];
            float a3 = res[3*S + (i64)i1*F + f];
            qs += a1 * ds;
            float tp = a2 * dp;
            qp0 += tp * uy; qp1 += tp * uz; qp2 += tp * ux;
            float td = a3 * dd;
            qd0 += td * (s3 * ux * uy);
            qd1 += td * (s3 * uy * uz);
            qd2 += td * (1.5f * uz * uz - 0.5f);
            qd3 += td * (s3 * ux * uz);
            qd4 += td * (0.5f * s3 * (ux*ux - uy*uy));
        }
        __syncthreads();
    }

    red[s][0][f] = qs;
    red[s][1][f] = qp0; red[s][2][f] = qp1; red[s][3][f] = qp2;
    red[s][4][f] = qd0; red[s][5][f] = qd1; red[s][6][f] = qd2;
    red[s][7][f] = qd3; red[s][8][f] = qd4;
    __syncthreads();
    if (s == 0){
        float sums[9];
        #pragma unroll
        for (int i = 0; i < 9; ++i) sums[i] = red[0][i][f] + red[1][i][f];
        inp[(i64)n*F + f] = res[(i64)n*F + f] + sums[0];
        #pragma unroll
        for (int mm = 0; mm < 8; ++mm)
            Q[(i64)mm * S + (i64)n*F + f] = f2bf(sums[1 + mm]);
    }
}

// ---------------------------------------------------------------------------
// Bilinear: for m-component, T1 = M1*Q_m, T2 = M2*Q_m (tiled GEMMs), then
// atomicAdd(inp, T1 .* T2).  M1/M2 = P or D depending on m.
// ---------------------------------------------------------------------------
__global__ __launch_bounds__(256)
void bilinear_kernel(const unsigned short* __restrict__ Q,
                     const float* __restrict__ P1, const float* __restrict__ P2,
                     const float* __restrict__ D1, const float* __restrict__ D2,
                     float* __restrict__ inp, int n)
{
    __shared__ float As[32][132];
    __shared__ float W1p[32][128];
    __shared__ float W2p[32][128];
    const int tid = threadIdx.x;
    const int m = blockIdx.y;
    const int a0 = blockIdx.x * 32;
    const float* M1 = (m < 3) ? P1 : D1;
    const float* M2 = (m < 3) ? P2 : D2;
    const unsigned short* A = Q + (i64)m * NA * F;
    const int fg = tid & 31, ag = tid >> 5;
    const int wi = tid >> 1, wc = tid & 1;

    { // stage Q tile bf16 -> f32
        int a = tid >> 3, seg = tid & 7;
        int nn = a0 + a;
        #pragma unroll
        for (int k = 0; k < 4; ++k){
            float4 v = make_float4(0.f,0.f,0.f,0.f);
            if (nn < n){
                ushort4 u = *(const ushort4*)(A + (i64)nn * F + seg*16 + k*4);
                v.x = bf2f(u.x); v.y = bf2f(u.y); v.z = bf2f(u.z); v.w = bf2f(u.w);
            }
            *(float4*)&As[a][seg*16 + k*4] = v;
        }
    }
    __syncthreads();

    float acc1[4][4], acc2[4][4];
    #pragma unroll
    for (int aa=0;aa<4;++aa)
        #pragma unroll
        for (int ff=0;ff<4;++ff){ acc1[aa][ff]=0.f; acc2[aa][ff]=0.f; }

    for (int jp = 0; jp < 4; ++jp){
        #pragma unroll
        for (int k = 0; k < 4; ++k){
            float4 v1 = *(const float4*)(M1 + (i64)wi * F + jp*32 + wc*16 + k*4);
            float4 v2 = *(const float4*)(M2 + (i64)wi * F + jp*32 + wc*16 + k*4);
            W1p[wc*16 + k*4 + 0][wi] = v1.x; W2p[wc*16 + k*4 + 0][wi] = v2.x;
            W1p[wc*16 + k*4 + 1][wi] = v1.y; W2p[wc*16 + k*4 + 1][wi] = v2.y;
            W1p[wc*16 + k*4 + 2][wi] = v1.z; W2p[wc*16 + k*4 + 2][wi] = v2.z;
            W1p[wc*16 + k*4 + 3][wi] = v1.w; W2p[wc*16 + k*4 + 3][wi] = v2.w;
        }
        __syncthreads();
        #pragma unroll
        for (int jj = 0; jj < 8; ++jj){
            float4 av[4], w1v[4], w2v[4];
            #pragma unroll
            for (int aa = 0; aa < 4; ++aa) av[aa] = *(const float4*)&As[ag*4 + aa][jp*32 + jj*4];
            #pragma unroll
            for (int d = 0; d < 4; ++d){
                w1v[d] = *(const float4*)&W1p[jj*4 + d][fg*4];
                w2v[d] = *(const float4*)&W2p[jj*4 + d][fg*4];
            }
            #pragma unroll
            for (int aa = 0; aa < 4; ++aa){
                acc1[aa][0] += av[aa].x*w1v[0].x + av[aa].y*w1v[1].x + av[aa].z*w1v[2].x + av[aa].w*w1v[3].x;
                acc1[aa][1] += av[aa].x*w1v[0].y + av[aa].y*w1v[1].y + av[aa].z*w1v[2].y + av[aa].w*w1v[3].y;
                acc1[aa][2] += av[aa].x*w1v[0].z + av[aa].y*w1v[1].z + av[aa].z*w1v[2].z + av[aa].w*w1v[3].z;
                acc1[aa][3] += av[aa].x*w1v[0].w + av[aa].y*w1v[1].w + av[aa].z*w1v[2].w + av[aa].w*w1v[3].w;
                acc2[aa][0] += av[aa].x*w2v[0].x + av[aa].y*w2v[1].x + av[aa].z*w2v[2].x + av[aa].w*w2v[3].x;
                acc2[aa][1] += av[aa].x*w2v[0].y + av[aa].y*w2v[1].y + av[aa].z*w2v[2].y + av[aa].w*w2v[3].y;
                acc2[aa][2] += av[aa].x*w2v[0].z + av[aa].y*w2v[1].z + av[aa].z*w2v[2].z + av[aa].w*w2v[3].z;
                acc2[aa][3] += av[aa].x*w2v[0].w + av[aa].y*w2v[1].w + av[aa].z*w2v[2].w + av[aa].w*w2v[3].w;
            }
        }
        __syncthreads();
    }

    #pragma unroll
    for (int aa = 0; aa < 4; ++aa){
        int nn = a0 + ag*4 + aa;
        if (nn >= n) continue;
        #pragma unroll
        for (int ff = 0; ff < 4; ++ff)
            atomicAdd(inp + (i64)nn * F + fg*4 + ff, acc1[aa][ff] * acc2[aa][ff]);
    }
}

// ---------------------------------------------------------------------------
extern "C" void kernel_launch(void* const* d_in, const int* in_sizes, int n_in,
                              void* d_out, int out_size, void* d_ws, size_t ws_size,
                              hipStream_t stream)
{
    const float* xyz     = (const float*)d_in[0];
    const float* x_tilde = (const float*)d_in[1];
    const int*   nbrs    = (const int*)d_in[2];
    const float* rm_W1 = (const float*)d_in[3],  *rm_b1 = (const float*)d_in[4];
    const float* rm_W2 = (const float*)d_in[5],  *rm_b2 = (const float*)d_in[6];
    const float* rm_W3 = (const float*)d_in[7],  *rm_b3 = (const float*)d_in[8];
    const float* rl_W1 = (const float*)d_in[9],  *rl_b1 = (const float*)d_in[10];
    const float* rl_W2 = (const float*)d_in[11], *rl_b2 = (const float*)d_in[12];
    const float* rl_W3 = (const float*)d_in[13], *rl_b3 = (const float*)d_in[14];
    const float* G_s = (const float*)d_in[15], *G_p = (const float*)d_in[16], *G_d = (const float*)d_in[17];
    const float* P_1 = (const float*)d_in[18], *P_2 = (const float*)d_in[19];
    const float* D_1 = (const float*)d_in[20], *D_2 = (const float*)d_in[21];
    const float* gamma_s = (const float*)d_in[22], *gamma_p = (const float*)d_in[23], *gamma_d = (const float*)d_in[24];
    const float* sw_a = (const float*)d_in[25], *sw_b = (const float*)d_in[26];

    const i64 S = (i64)NA * F;
    float* res  = (float*)d_ws;               // 4S floats
    float* inp  = res + 4 * S;                // S floats
    unsigned short* Q = (unsigned short*)(inp + S);  // 8S ushorts (=4S floats)
    float* rec  = inp + S + 4 * S;            // NE*RECW floats
    int* cnt    = (int*)(rec + (i64)NE * RECW);
    int* fill   = cnt + NA;
    int* offs   = fill + NA;                  // NA+1 ints

    hipMemsetAsync(cnt, 0, 2 * NA * sizeof(int), stream);

    const int NT = (NA + 31) / 32;   // 157

    // residual MLP: 4 channels fused (x -> res[c])
    mlp3_kernel<0,1,2,1,1><<<dim3(NT,4), 256, 0, stream>>>(
        x_tilde, rm_W1, rm_b1, rm_W2, rm_b2, rm_W3, rm_b3, res, S, sw_a, sw_b, NA);

    // CSR over ACTIVE edges + per-edge records
    prep_count<<<(NE+255)/256, 256, 0, stream>>>(xyz, nbrs, cnt);
    scan_kernel<<<1, 1024, 0, stream>>>(cnt, offs);
    prep_fill<<<(NE+255)/256, 256, 0, stream>>>(xyz, nbrs, offs, fill,
                                                gamma_s, gamma_p, gamma_d, rec);

    // moments + inp = res0 + q_s
    q_gather<<<NA, 256, 0, stream>>>(rec, offs, res, G_s, G_p, G_d, inp, Q);

    // bilinear P/D contraction accumulated into inp
    bilinear_kernel<<<dim3(NT,8), 256, 0, stream>>>(Q, P_1, P_2, D_1, D_2, inp, NA);

    // final MLP (inp -> out)
    mlp3_kernel<3,4,5,1,0><<<dim3(NT,1), 256, 0, stream>>>(
        inp, rl_W1, rl_b1, rl_W2, rl_b2, rl_W3, rl_b3, (float*)d_out, 0, sw_a, sw_b, NA);
}

// Round 3
// 240.946 us; speedup vs baseline: 1.7426x; 1.1374x over previous
//
#include <hip/hip_runtime.h>
#include <hip/hip_bf16.h>
#include <math.h>

#define NA 5000
#define NE 100000
#define F 128
#define KB 16
#define RCUT 5.0f
#define RECW 28   // words per edge record: i1, ux,uy,uz, 24 bf16-pair words

typedef long long i64;

__device__ __forceinline__ float swish_f(float t, float a, float b){
    return a * t / (1.0f + __expf(-b * t));
}
__device__ __forceinline__ float bf2f(unsigned short u){
    return __uint_as_float(((unsigned)u) << 16);
}
__device__ __forceinline__ unsigned short f2bf(float x){
    unsigned b = __float_as_uint(x);
    return (unsigned short)((b + 0x8000u) >> 16);
}
__device__ __forceinline__ unsigned pack2(float a, float b){
    return (unsigned)f2bf(a) | ((unsigned)f2bf(b) << 16);
}

// ---------------------------------------------------------------------------
// Shared tiled-GEMM core: C[32 atoms][128 f] += W(128x128) * As(K-major in LDS)
// 256 threads: fg = tid&31 (4 feats), ag = tid>>5 (4 atoms) -> 4x4 micro-tile.
// ---------------------------------------------------------------------------
__device__ __forceinline__ void gemm128(const float (*As)[132], float (*Wp)[128],
                                        const float* __restrict__ Wg,
                                        float acc[4][4], int fg, int ag, int wi, int wc)
{
    for (int jp = 0; jp < 4; ++jp){
        #pragma unroll
        for (int k = 0; k < 4; ++k){
            float4 v = *(const float4*)(Wg + (i64)wi * F + jp * 32 + wc * 16 + k * 4);
            Wp[wc*16 + k*4 + 0][wi] = v.x;
            Wp[wc*16 + k*4 + 1][wi] = v.y;
            Wp[wc*16 + k*4 + 2][wi] = v.z;
            Wp[wc*16 + k*4 + 3][wi] = v.w;
        }
        __syncthreads();
        #pragma unroll
        for (int jj = 0; jj < 8; ++jj){
            float4 av[4], wv[4];
            #pragma unroll
            for (int aa = 0; aa < 4; ++aa) av[aa] = *(const float4*)&As[ag*4 + aa][jp*32 + jj*4];
            #pragma unroll
            for (int d = 0; d < 4; ++d) wv[d] = *(const float4*)&Wp[jj*4 + d][fg*4];
            #pragma unroll
            for (int aa = 0; aa < 4; ++aa){
                acc[aa][0] += av[aa].x*wv[0].x + av[aa].y*wv[1].x + av[aa].z*wv[2].x + av[aa].w*wv[3].x;
                acc[aa][1] += av[aa].x*wv[0].y + av[aa].y*wv[1].y + av[aa].z*wv[2].y + av[aa].w*wv[3].y;
                acc[aa][2] += av[aa].x*wv[0].z + av[aa].y*wv[1].z + av[aa].z*wv[2].z + av[aa].w*wv[3].z;
                acc[aa][3] += av[aa].x*wv[0].w + av[aa].y*wv[1].w + av[aa].z*wv[2].w + av[aa].w*wv[3].w;
            }
        }
        __syncthreads();
    }
}

// ---------------------------------------------------------------------------
// Fused 3-stage MLP
// ---------------------------------------------------------------------------
template<int S0,int S1,int S2,int ADD2,int ADD3>
__global__ __launch_bounds__(256)
void mlp3_kernel(const float* __restrict__ in,
                 const float* __restrict__ W1, const float* __restrict__ b1,
                 const float* __restrict__ W2, const float* __restrict__ b2,
                 const float* __restrict__ W3, const float* __restrict__ b3,
                 float* __restrict__ out, i64 out_cstride,
                 const float* __restrict__ sw_a, const float* __restrict__ sw_b,
                 int n)
{
    __shared__ float As[32][132];
    __shared__ float Wp[32][128];
    const int tid = threadIdx.x;
    const int c = blockIdx.y;
    const int a0 = blockIdx.x * 32;
    const int fg = tid & 31, ag = tid >> 5;
    const int wi = tid >> 1, wc = tid & 1;

    const float* Wc1 = W1 + (i64)c * F * F; const float* bc1 = b1 + c * F;
    const float* Wc2 = W2 + (i64)c * F * F; const float* bc2 = b2 + c * F;
    const float* Wc3 = W3 + (i64)c * F * F; const float* bc3 = b3 + c * F;

    {
        int a = tid >> 3, seg = tid & 7;
        int nn = a0 + a;
        float aS = sw_a[S0], bS = sw_b[S0];
        #pragma unroll
        for (int k = 0; k < 4; ++k){
            float4 v = make_float4(0.f,0.f,0.f,0.f);
            if (nn < n) v = *(const float4*)(in + (i64)nn * F + seg*16 + k*4);
            v.x = swish_f(v.x, aS, bS); v.y = swish_f(v.y, aS, bS);
            v.z = swish_f(v.z, aS, bS); v.w = swish_f(v.w, aS, bS);
            *(float4*)&As[a][seg*16 + k*4] = v;
        }
    }
    __syncthreads();

    float acc[4][4];
    #pragma unroll
    for (int aa=0;aa<4;++aa) { acc[aa][0]=acc[aa][1]=acc[aa][2]=acc[aa][3]=0.f; }
    gemm128(As, Wp, Wc1, acc, fg, ag, wi, wc);

    {
        float aS = sw_a[S1], bS = sw_b[S1];
        float4 bv = *(const float4*)(bc1 + fg*4);
        #pragma unroll
        for (int aa=0;aa<4;++aa){
            float4 o;
            o.x = swish_f(acc[aa][0] + bv.x, aS, bS);
            o.y = swish_f(acc[aa][1] + bv.y, aS, bS);
            o.z = swish_f(acc[aa][2] + bv.z, aS, bS);
            o.w = swish_f(acc[aa][3] + bv.w, aS, bS);
            *(float4*)&As[ag*4 + aa][fg*4] = o;
        }
    }
    __syncthreads();

    #pragma unroll
    for (int aa=0;aa<4;++aa) { acc[aa][0]=acc[aa][1]=acc[aa][2]=acc[aa][3]=0.f; }
    gemm128(As, Wp, Wc2, acc, fg, ag, wi, wc);

    {
        float aS = sw_a[S2], bS = sw_b[S2];
        float4 bv = *(const float4*)(bc2 + fg*4);
        #pragma unroll
        for (int aa=0;aa<4;++aa){
            int nn = a0 + ag*4 + aa;
            float4 xv = make_float4(0.f,0.f,0.f,0.f);
            if (ADD2 && nn < n) xv = *(const float4*)(in + (i64)nn * F + fg*4);
            float4 o;
            o.x = swish_f(acc[aa][0] + bv.x + xv.x, aS, bS);
            o.y = swish_f(acc[aa][1] + bv.y + xv.y, aS, bS);
            o.z = swish_f(acc[aa][2] + bv.z + xv.z, aS, bS);
            o.w = swish_f(acc[aa][3] + bv.w + xv.w, aS, bS);
            *(float4*)&As[ag*4 + aa][fg*4] = o;
        }
    }
    __syncthreads();

    #pragma unroll
    for (int aa=0;aa<4;++aa) { acc[aa][0]=acc[aa][1]=acc[aa][2]=acc[aa][3]=0.f; }
    gemm128(As, Wp, Wc3, acc, fg, ag, wi, wc);

    {
        float4 bv = *(const float4*)(bc3 + fg*4);
        #pragma unroll
        for (int aa=0;aa<4;++aa){
            int nn = a0 + ag*4 + aa;
            if (nn >= n) continue;
            float4 xv = make_float4(0.f,0.f,0.f,0.f);
            if (ADD3) xv = *(const float4*)(in + (i64)nn * F + fg*4);
            float4 o;
            o.x = acc[aa][0] + bv.x + xv.x;
            o.y = acc[aa][1] + bv.y + xv.y;
            o.z = acc[aa][2] + bv.z + xv.z;
            o.w = acc[aa][3] + bv.w + xv.w;
            *(float4*)(out + (i64)c * out_cstride + (i64)nn * F + fg*4) = o;
        }
    }
}

// ---------------------------------------------------------------------------
// Edge prep
// ---------------------------------------------------------------------------
__global__ void prep_count(const float* __restrict__ xyz, const int* __restrict__ nbrs,
                           int* __restrict__ cnt){
    int e = blockIdx.x * 256 + threadIdx.x;
    if (e >= NE) return;
    int i0 = nbrs[2*e], i1 = nbrs[2*e+1];
    float dx = xyz[3*i1]   - xyz[3*i0];
    float dy = xyz[3*i1+1] - xyz[3*i0+1];
    float dz = xyz[3*i1+2] - xyz[3*i0+2];
    float r = sqrtf(dx*dx + dy*dy + dz*dz + 3e-15f);
    if (r < RCUT) atomicAdd(&cnt[i0], 1);
}

__global__ __launch_bounds__(1024)
void scan_kernel(const int* __restrict__ cnt, int* __restrict__ offs){
    __shared__ int part[1024];
    int t = threadIdx.x;
    int loc[5]; int s = 0;
    #pragma unroll
    for (int c = 0; c < 5; ++c){
        int i = t * 5 + c;
        int v = (i < NA) ? cnt[i] : 0;
        loc[c] = s; s += v;
    }
    part[t] = s;
    __syncthreads();
    for (int off = 1; off < 1024; off <<= 1){
        int v = (t >= off) ? part[t - off] : 0;
        __syncthreads();
        part[t] += v;
        __syncthreads();
    }
    int bs = (t == 0) ? 0 : part[t - 1];
    #pragma unroll
    for (int c = 0; c < 5; ++c){
        int i = t * 5 + c;
        if (i <= NA) offs[i] = bs + loc[c];
    }
}

__device__ __forceinline__ void basis16(float r, float g, float fcut, float* b){
    const float C[KB] = {1.f,15.f,105.f,455.f,1365.f,3003.f,5005.f,6435.f,
                         6435.f,5005.f,3003.f,1365.f,455.f,105.f,15.f,1.f};
    float e = __expf(-fmaxf(g, 0.f) * r);
    float one = 1.f - e;
    float ep = 1.f;
    #pragma unroll
    for (int k = 0; k < KB; ++k){ b[k] = C[k] * ep * fcut; ep *= e; }
    float op = 1.f;
    #pragma unroll
    for (int k = KB-1; k >= 0; --k){ b[k] *= op; op *= one; }
}

__global__ void prep_fill(const float* __restrict__ xyz, const int* __restrict__ nbrs,
                          const int* __restrict__ offs, int* __restrict__ fill,
                          const float* __restrict__ gs, const float* __restrict__ gp,
                          const float* __restrict__ gd, float* __restrict__ rec){
    int e = blockIdx.x * 256 + threadIdx.x;
    if (e >= NE) return;
    int i0 = nbrs[2*e], i1 = nbrs[2*e+1];
    float dx = xyz[3*i1]   - xyz[3*i0];
    float dy = xyz[3*i1+1] - xyz[3*i0+1];
    float dz = xyz[3*i1+2] - xyz[3*i0+2];
    float r2 = dx*dx + dy*dy + dz*dz + 3e-15f;
    float r = sqrtf(r2);
    if (r >= RCUT) return;
    int pos = offs[i0] + atomicAdd(&fill[i0], 1);
    float* R = rec + (i64)pos * RECW;
    float ir = 1.f / r;
    R[0] = __int_as_float(i1);
    R[1] = dx * ir; R[2] = dy * ir; R[3] = dz * ir;
    float fcut = __expf(-r2 / ((RCUT - r) * (RCUT + r)));
    float bs[KB], bp[KB], bd[KB];
    basis16(r, gs[0], fcut, bs);
    basis16(r, gp[0], fcut, bp);
    basis16(r, gd[0], fcut, bd);
    unsigned* RW = (unsigned*)(R + 4);
    #pragma unroll
    for (int k = 0; k < 8; ++k) RW[k]      = pack2(bs[2*k], bs[2*k+1]);
    #pragma unroll
    for (int k = 0; k < 8; ++k) RW[8 + k]  = pack2(bp[2*k], bp[2*k+1]);
    #pragma unroll
    for (int k = 0; k < 8; ++k) RW[16 + k] = pack2(bd[2*k], bd[2*k+1]);
}

// ---------------------------------------------------------------------------
// Moment gather
// ---------------------------------------------------------------------------
__global__ __launch_bounds__(256)
void q_gather(const float* __restrict__ rec, const int* __restrict__ offs,
              const float* __restrict__ res,
              const float* __restrict__ Gs, const float* __restrict__ Gp,
              const float* __restrict__ Gd,
              float* __restrict__ inp, unsigned short* __restrict__ Q)
{
    const int n = blockIdx.x;
    const int tid = threadIdx.x;
    const int s = tid >> 7;
    const int f = tid & 127;
    const i64 S = (i64)NA * F;

    float G0[KB], G1[KB], G2[KB];
    #pragma unroll
    for (int q4 = 0; q4 < 4; ++q4){
        *(float4*)&G0[q4*4] = *(const float4*)(Gs + f*KB + q4*4);
        *(float4*)&G1[q4*4] = *(const float4*)(Gp + f*KB + q4*4);
        *(float4*)&G2[q4*4] = *(const float4*)(Gd + f*KB + q4*4);
    }

    float qs = 0.f;
    float qp0=0.f, qp1=0.f, qp2=0.f;
    float qd0=0.f, qd1=0.f, qd2=0.f, qd3=0.f, qd4=0.f;

    __shared__ float recs[16 * RECW];
    __shared__ float red[2][9][128];

    const int e0 = offs[n], e1 = offs[n+1];
    const int cnt_e = e1 - e0;
    const float s3 = 1.7320508075688772f;

    for (int base = 0; base < cnt_e; base += 16){
        int mrec = min(16, cnt_e - base);
        for (int w = tid; w < mrec * RECW; w += 256)
            recs[w] = rec[(i64)(e0 + base) * RECW + w];
        __syncthreads();
        for (int j = s; j < mrec; j += 2){
            const float* R = &recs[j * RECW];
            int i1 = __float_as_int(R[0]);
            float ux = R[1], uy = R[2], uz = R[3];
            const unsigned* bw = (const unsigned*)(R + 4);
            float ds = 0.f, dp = 0.f, dd = 0.f;
            #pragma unroll
            for (int k = 0; k < 8; ++k){
                unsigned w = bw[k];
                ds += G0[2*k] * __uint_as_float(w << 16) + G0[2*k+1] * __uint_as_float(w & 0xffff0000u);
            }
            #pragma unroll
            for (int k = 0; k < 8; ++k){
                unsigned w = bw[8+k];
                dp += G1[2*k] * __uint_as_float(w << 16) + G1[2*k+1] * __uint_as_float(w & 0xffff0000u);
            }
            #pragma unroll
            for (int k = 0; k < 8; ++k){
                unsigned w = bw[16+k];
                dd += G2[2*k] * __uint_as_float(w << 16) + G2[2*k+1] * __uint_as_float(w & 0xffff0000u);
            }
            float a1 = res[S   + (i64)i1*F + f];
            float a2 = res[2*S + (i64)i1*F + f];
            float a3 = res[3*S + (i64)i1*F + f];
            qs += a1 * ds;
            float tp = a2 * dp;
            qp0 += tp * uy; qp1 += tp * uz; qp2 += tp * ux;
            float td = a3 * dd;
            qd0 += td * (s3 * ux * uy);
            qd1 += td * (s3 * uy * uz);
            qd2 += td * (1.5f * uz * uz - 0.5f);
            qd3 += td * (s3 * ux * uz);
            qd4 += td * (0.5f * s3 * (ux*ux - uy*uy));
        }
        __syncthreads();
    }

    red[s][0][f] = qs;
    red[s][1][f] = qp0; red[s][2][f] = qp1; red[s][3][f] = qp2;
    red[s][4][f] = qd0; red[s][5][f] = qd1; red[s][6][f] = qd2;
    red[s][7][f] = qd3; red[s][8][f] = qd4;
    __syncthreads();
    if (s == 0){
        float sums[9];
        #pragma unroll
        for (int i = 0; i < 9; ++i) sums[i] = red[0][i][f] + red[1][i][f];
        inp[(i64)n*F + f] = res[(i64)n*F + f] + sums[0];
        #pragma unroll
        for (int mm = 0; mm < 8; ++mm)
            Q[(i64)mm * S + (i64)n*F + f] = f2bf(sums[1 + mm]);
    }
}

// ---------------------------------------------------------------------------
// Bilinear: T1 = M1*Q_m, T2 = M2*Q_m per m; write T1.*T2 to part[m] (bf16).
// No atomics: each (atom-tile, m) block owns its slice of part[m].
// ---------------------------------------------------------------------------
__global__ __launch_bounds__(256)
void bilinear_kernel(const unsigned short* __restrict__ Q,
                     const float* __restrict__ P1, const float* __restrict__ P2,
                     const float* __restrict__ D1, const float* __restrict__ D2,
                     unsigned short* __restrict__ part, int n)
{
    __shared__ float As[32][132];
    __shared__ float W1p[32][128];
    __shared__ float W2p[32][128];
    const int tid = threadIdx.x;
    const int m = blockIdx.y;
    const int a0 = blockIdx.x * 32;
    const float* M1 = (m < 3) ? P1 : D1;
    const float* M2 = (m < 3) ? P2 : D2;
    const i64 S = (i64)NA * F;
    const unsigned short* A = Q + (i64)m * S;
    const int fg = tid & 31, ag = tid >> 5;
    const int wi = tid >> 1, wc = tid & 1;

    {
        int a = tid >> 3, seg = tid & 7;
        int nn = a0 + a;
        #pragma unroll
        for (int k = 0; k < 4; ++k){
            float4 v = make_float4(0.f,0.f,0.f,0.f);
            if (nn < n){
                ushort4 u = *(const ushort4*)(A + (i64)nn * F + seg*16 + k*4);
                v.x = bf2f(u.x); v.y = bf2f(u.y); v.z = bf2f(u.z); v.w = bf2f(u.w);
            }
            *(float4*)&As[a][seg*16 + k*4] = v;
        }
    }
    __syncthreads();

    float acc1[4][4], acc2[4][4];
    #pragma unroll
    for (int aa=0;aa<4;++aa)
        #pragma unroll
        for (int ff=0;ff<4;++ff){ acc1[aa][ff]=0.f; acc2[aa][ff]=0.f; }

    for (int jp = 0; jp < 4; ++jp){
        #pragma unroll
        for (int k = 0; k < 4; ++k){
            float4 v1 = *(const float4*)(M1 + (i64)wi * F + jp*32 + wc*16 + k*4);
            float4 v2 = *(const float4*)(M2 + (i64)wi * F + jp*32 + wc*16 + k*4);
            W1p[wc*16 + k*4 + 0][wi] = v1.x; W2p[wc*16 + k*4 + 0][wi] = v2.x;
            W1p[wc*16 + k*4 + 1][wi] = v1.y; W2p[wc*16 + k*4 + 1][wi] = v2.y;
            W1p[wc*16 + k*4 + 2][wi] = v1.z; W2p[wc*16 + k*4 + 2][wi] = v2.z;
            W1p[wc*16 + k*4 + 3][wi] = v1.w; W2p[wc*16 + k*4 + 3][wi] = v2.w;
        }
        __syncthreads();
        #pragma unroll
        for (int jj = 0; jj < 8; ++jj){
            float4 av[4], w1v[4], w2v[4];
            #pragma unroll
            for (int aa = 0; aa < 4; ++aa) av[aa] = *(const float4*)&As[ag*4 + aa][jp*32 + jj*4];
            #pragma unroll
            for (int d = 0; d < 4; ++d){
                w1v[d] = *(const float4*)&W1p[jj*4 + d][fg*4];
                w2v[d] = *(const float4*)&W2p[jj*4 + d][fg*4];
            }
            #pragma unroll
            for (int aa = 0; aa < 4; ++aa){
                acc1[aa][0] += av[aa].x*w1v[0].x + av[aa].y*w1v[1].x + av[aa].z*w1v[2].x + av[aa].w*w1v[3].x;
                acc1[aa][1] += av[aa].x*w1v[0].y + av[aa].y*w1v[1].y + av[aa].z*w1v[2].y + av[aa].w*w1v[3].y;
                acc1[aa][2] += av[aa].x*w1v[0].z + av[aa].y*w1v[1].z + av[aa].z*w1v[2].z + av[aa].w*w1v[3].z;
                acc1[aa][3] += av[aa].x*w1v[0].w + av[aa].y*w1v[1].w + av[aa].z*w1v[2].w + av[aa].w*w1v[3].w;
                acc2[aa][0] += av[aa].x*w2v[0].x + av[aa].y*w2v[1].x + av[aa].z*w2v[2].x + av[aa].w*w2v[3].x;
                acc2[aa][1] += av[aa].x*w2v[0].y + av[aa].y*w2v[1].y + av[aa].z*w2v[2].y + av[aa].w*w2v[3].y;
                acc2[aa][2] += av[aa].x*w2v[0].z + av[aa].y*w2v[1].z + av[aa].z*w2v[2].z + av[aa].w*w2v[3].z;
                acc2[aa][3] += av[aa].x*w2v[0].w + av[aa].y*w2v[1].w + av[aa].z*w2v[2].w + av[aa].w*w2v[3].w;
            }
        }
        __syncthreads();
    }

    #pragma unroll
    for (int aa = 0; aa < 4; ++aa){
        int nn = a0 + ag*4 + aa;
        if (nn >= n) continue;
        ushort4 o;
        o.x = f2bf(acc1[aa][0] * acc2[aa][0]);
        o.y = f2bf(acc1[aa][1] * acc2[aa][1]);
        o.z = f2bf(acc1[aa][2] * acc2[aa][2]);
        o.w = f2bf(acc1[aa][3] * acc2[aa][3]);
        *(ushort4*)(part + (i64)m * S + (i64)nn * F + fg*4) = o;
    }
}

// ---------------------------------------------------------------------------
// inp += sum_m part[m]
// ---------------------------------------------------------------------------
__global__ __launch_bounds__(256)
void combine_kernel(float* __restrict__ inp, const unsigned short* __restrict__ part){
    const i64 S = (i64)NA * F;
    i64 idx = ((i64)blockIdx.x * 256 + threadIdx.x) * 4;
    if (idx >= S) return;
    float4 v = *(float4*)(inp + idx);
    #pragma unroll
    for (int m = 0; m < 8; ++m){
        ushort4 u = *(const ushort4*)(part + (i64)m * S + idx);
        v.x += bf2f(u.x); v.y += bf2f(u.y); v.z += bf2f(u.z); v.w += bf2f(u.w);
    }
    *(float4*)(inp + idx) = v;
}

// ---------------------------------------------------------------------------
extern "C" void kernel_launch(void* const* d_in, const int* in_sizes, int n_in,
                              void* d_out, int out_size, void* d_ws, size_t ws_size,
                              hipStream_t stream)
{
    const float* xyz     = (const float*)d_in[0];
    const float* x_tilde = (const float*)d_in[1];
    const int*   nbrs    = (const int*)d_in[2];
    const float* rm_W1 = (const float*)d_in[3],  *rm_b1 = (const float*)d_in[4];
    const float* rm_W2 = (const float*)d_in[5],  *rm_b2 = (const float*)d_in[6];
    const float* rm_W3 = (const float*)d_in[7],  *rm_b3 = (const float*)d_in[8];
    const float* rl_W1 = (const float*)d_in[9],  *rl_b1 = (const float*)d_in[10];
    const float* rl_W2 = (const float*)d_in[11], *rl_b2 = (const float*)d_in[12];
    const float* rl_W3 = (const float*)d_in[13], *rl_b3 = (const float*)d_in[14];
    const float* G_s = (const float*)d_in[15], *G_p = (const float*)d_in[16], *G_d = (const float*)d_in[17];
    const float* P_1 = (const float*)d_in[18], *P_2 = (const float*)d_in[19];
    const float* D_1 = (const float*)d_in[20], *D_2 = (const float*)d_in[21];
    const float* gamma_s = (const float*)d_in[22], *gamma_p = (const float*)d_in[23], *gamma_d = (const float*)d_in[24];
    const float* sw_a = (const float*)d_in[25], *sw_b = (const float*)d_in[26];

    const i64 S = (i64)NA * F;
    float* res  = (float*)d_ws;               // 4S floats
    float* inp  = res + 4 * S;                // S floats
    unsigned short* Q = (unsigned short*)(inp + S);  // 8S ushorts (=4S floats)
    float* rec  = inp + S + 4 * S;            // NE*RECW floats; reused as part[]
    unsigned short* part = (unsigned short*)rec;     // 8S ushorts (fits in NE*RECW floats)
    int* cnt    = (int*)(rec + (i64)NE * RECW);
    int* fill   = cnt + NA;
    int* offs   = fill + NA;                  // NA+1 ints

    hipMemsetAsync(cnt, 0, 2 * NA * sizeof(int), stream);

    const int NT = (NA + 31) / 32;   // 157

    // residual MLP: 4 channels fused (x -> res[c])
    mlp3_kernel<0,1,2,1,1><<<dim3(NT,4), 256, 0, stream>>>(
        x_tilde, rm_W1, rm_b1, rm_W2, rm_b2, rm_W3, rm_b3, res, S, sw_a, sw_b, NA);

    // CSR over ACTIVE edges + per-edge records
    prep_count<<<(NE+255)/256, 256, 0, stream>>>(xyz, nbrs, cnt);
    scan_kernel<<<1, 1024, 0, stream>>>(cnt, offs);
    prep_fill<<<(NE+255)/256, 256, 0, stream>>>(xyz, nbrs, offs, fill,
                                                gamma_s, gamma_p, gamma_d, rec);

    // moments + inp = res0 + q_s   (rec fully consumed here)
    q_gather<<<NA, 256, 0, stream>>>(rec, offs, res, G_s, G_p, G_d, inp, Q);

    // bilinear P/D contraction -> part[m] (bf16, aliases rec region)
    bilinear_kernel<<<dim3(NT,8), 256, 0, stream>>>(Q, P_1, P_2, D_1, D_2, part, NA);

    // inp += sum_m part[m]
    combine_kernel<<<(int)((S/4 + 255)/256), 256, 0, stream>>>(inp, part);

    // final MLP (inp -> out)
    mlp3_kernel<3,4,5,1,0><<<dim3(NT,1), 256, 0, stream>>>(
        inp, rl_W1, rl_b1, rl_W2, rl_b2, rl_W3, rl_b3, (float*)d_out, 0, sw_a, sw_b, NA);
}

// Round 4
// 107.741 us; speedup vs baseline: 3.8970x; 2.2363x over previous
//
#include <hip/hip_runtime.h>
#include <hip/hip_bf16.h>
#include <math.h>

#define NA 5000
#define NE 100000
#define F 128
#define KB 16
#define RCUT 5.0f
#define RECW 28   // words per edge record: i1, ux,uy,uz, 24 bf16-pair words

typedef long long i64;
typedef __attribute__((ext_vector_type(8))) short bf16x8;   // 8 bf16 = 4 VGPRs
typedef __attribute__((ext_vector_type(4))) float f32x4;

__device__ __forceinline__ float swish_f(float t, float a, float b){
    return a * t / (1.0f + __expf(-b * t));
}
__device__ __forceinline__ float bf2f(unsigned short u){
    return __uint_as_float(((unsigned)u) << 16);
}
__device__ __forceinline__ unsigned short f2bf(float x){
    unsigned b = __float_as_uint(x);
    return (unsigned short)((b + 0x8000u) >> 16);
}
__device__ __forceinline__ unsigned pack2(float a, float b){
    return (unsigned)f2bf(a) | ((unsigned)f2bf(b) << 16);
}
// XOR swizzle: row-major [32][128] bf16 tile, 256 B/row. Spreads the
// 16-lane same-column reads across 8 16B slots -> 2-way (free).
__device__ __forceinline__ int swz(int row, int byte_in_row){
    return row * 256 + (byte_in_row ^ ((row & 7) << 4));
}

// ---------------------------------------------------------------------------
// MFMA GEMM stage: acc[mt][ntl] += act(32xK=128, LDS bf16 swizzled) x W^T.
// B-frags straight from global bf16 W[i][j] (row-major; B[k][col]=W[col][k]).
// 4 waves, wave covers cols [wave*32, wave*32+32).
// ---------------------------------------------------------------------------
__device__ __forceinline__ void gemm_stage(const unsigned short* __restrict__ Wb,
                                           const short* act_lds, f32x4 acc[2][2],
                                           int lane, int wave)
{
    bf16x8 B[2][4], A[2][4];
    const int cl = lane & 15, kh = lane >> 4;
    #pragma unroll
    for (int ntl = 0; ntl < 2; ++ntl){
        const unsigned short* wp = Wb + (i64)(wave * 32 + ntl * 16 + cl) * F + kh * 8;
        #pragma unroll
        for (int kb = 0; kb < 4; ++kb)
            B[ntl][kb] = *(const bf16x8*)(wp + kb * 32);
    }
    #pragma unroll
    for (int mt = 0; mt < 2; ++mt){
        int row = mt * 16 + cl;
        #pragma unroll
        for (int kb = 0; kb < 4; ++kb)
            A[mt][kb] = *(const bf16x8*)((const char*)act_lds + swz(row, kb * 64 + kh * 16));
    }
    #pragma unroll
    for (int mt = 0; mt < 2; ++mt)
        #pragma unroll
        for (int ntl = 0; ntl < 2; ++ntl)
            #pragma unroll
            for (int kb = 0; kb < 4; ++kb)
                acc[mt][ntl] = __builtin_amdgcn_mfma_f32_16x16x32_bf16(
                    A[mt][kb], B[ntl][kb], acc[mt][ntl], 0, 0, 0);
}

__device__ __forceinline__ void zero_acc(f32x4 acc[2][2]){
    #pragma unroll
    for (int a = 0; a < 2; ++a)
        #pragma unroll
        for (int b = 0; b < 2; ++b)
            acc[a][b] = (f32x4){0.f, 0.f, 0.f, 0.f};
}

// epilogue: z = acc + bias (+resid), swish -> bf16 -> act_lds (as next A)
__device__ __forceinline__ void epi_lds(f32x4 acc[2][2], const float* __restrict__ bc,
                                        const float* resid_lds, int use_resid,
                                        float aS, float bS, short* act_lds,
                                        int lane, int wave)
{
    const int cl = lane & 15, r4 = (lane >> 4) * 4;
    #pragma unroll
    for (int ntl = 0; ntl < 2; ++ntl){
        int col = wave * 32 + ntl * 16 + cl;
        float bv = bc[col];
        #pragma unroll
        for (int mt = 0; mt < 2; ++mt){
            #pragma unroll
            for (int j = 0; j < 4; ++j){
                int row = mt * 16 + r4 + j;
                float z = acc[mt][ntl][j] + bv;
                if (use_resid) z += resid_lds[row * 132 + col];
                z = swish_f(z, aS, bS);
                *(short*)((char*)act_lds + swz(row, col * 2)) = (short)f2bf(z);
            }
        }
    }
}

// ---------------------------------------------------------------------------
// Fused 3-stage MLP, MFMA core. Block = 256 thr (4 waves) x 32 atoms.
// ---------------------------------------------------------------------------
template<int S0, int S1, int S2, int ADD2, int ADD3, int ADDPART>
__global__ __launch_bounds__(256)
void mlp3_mfma(const float* __restrict__ in, const unsigned short* __restrict__ part,
               const unsigned short* __restrict__ W1b, const float* __restrict__ b1,
               const unsigned short* __restrict__ W2b, const float* __restrict__ b2,
               const unsigned short* __restrict__ W3b, const float* __restrict__ b3,
               float* __restrict__ out, i64 out_cstride,
               const float* __restrict__ sw_a, const float* __restrict__ sw_b, int n)
{
    __shared__ short act_lds[32 * 128];     // swizzled bf16 activations
    __shared__ float resid_lds[32 * 132];   // padded f32 residual copy
    const int tid = threadIdx.x;
    const int lane = tid & 63, wave = tid >> 6;
    const int c = blockIdx.y;
    const int a0 = blockIdx.x * 32;
    const i64 S = (i64)NA * F;

    const unsigned short* Wc1 = W1b + (i64)c * F * F;
    const unsigned short* Wc2 = W2b + (i64)c * F * F;
    const unsigned short* Wc3 = W3b + (i64)c * F * F;
    const float* bc1 = b1 + c * F;
    const float* bc2 = b2 + c * F;
    const float* bc3 = b3 + c * F;

    { // stage input: resid (f32) + swish_S0 -> bf16 act
        float aS = sw_a[S0], bS = sw_b[S0];
        #pragma unroll
        for (int it = 0; it < 4; ++it){
            int ch = tid + it * 256;         // 1024 float4-chunks
            int row = ch >> 5, j4 = ch & 31;
            int g = a0 + row;
            float4 v = make_float4(0.f, 0.f, 0.f, 0.f);
            if (g < n){
                v = *(const float4*)(in + (i64)g * F + j4 * 4);
                if (ADDPART){
                    #pragma unroll
                    for (int m = 0; m < 8; ++m){
                        ushort4 u = *(const ushort4*)(part + (i64)m * S + (i64)g * F + j4 * 4);
                        v.x += bf2f(u.x); v.y += bf2f(u.y);
                        v.z += bf2f(u.z); v.w += bf2f(u.w);
                    }
                }
            }
            *(float4*)&resid_lds[row * 132 + j4 * 4] = v;
            uint2 p;
            p.x = pack2(swish_f(v.x, aS, bS), swish_f(v.y, aS, bS));
            p.y = pack2(swish_f(v.z, aS, bS), swish_f(v.w, aS, bS));
            *(uint2*)((char*)act_lds + swz(row, j4 * 8)) = p;
        }
    }
    __syncthreads();

    f32x4 acc[2][2];
    // stage 1: z1 = W1 act0 + b1; act1 = sw_S1(z1)
    zero_acc(acc);
    gemm_stage(Wc1, act_lds, acc, lane, wave);
    __syncthreads();
    epi_lds(acc, bc1, resid_lds, 0, sw_a[S1], sw_b[S1], act_lds, lane, wave);
    __syncthreads();

    // stage 2: z2 = W2 act1 + b2 (+x); act2 = sw_S2(z2)
    zero_acc(acc);
    gemm_stage(Wc2, act_lds, acc, lane, wave);
    __syncthreads();
    epi_lds(acc, bc2, resid_lds, ADD2, sw_a[S2], sw_b[S2], act_lds, lane, wave);
    __syncthreads();

    // stage 3: z3 = W3 act2 + b3 (+x) -> out (f32)
    zero_acc(acc);
    gemm_stage(Wc3, act_lds, acc, lane, wave);
    {
        const int cl = lane & 15, r4 = (lane >> 4) * 4;
        #pragma unroll
        for (int ntl = 0; ntl < 2; ++ntl){
            int col = wave * 32 + ntl * 16 + cl;
            float bv = bc3[col];
            #pragma unroll
            for (int mt = 0; mt < 2; ++mt){
                #pragma unroll
                for (int j = 0; j < 4; ++j){
                    int row = mt * 16 + r4 + j;
                    int g = a0 + row;
                    if (g >= n) continue;
                    float z = acc[mt][ntl][j] + bv;
                    if (ADD3) z += resid_lds[row * 132 + col];
                    out[(i64)c * out_cstride + (i64)g * F + col] = z;
                }
            }
        }
    }
}

// ---------------------------------------------------------------------------
// Bilinear, MFMA core: per (atom-tile, m): acc1 = M1*Q_m, acc2 = M2*Q_m,
// part[m] = bf16(acc1 .* acc2). No atomics.
// ---------------------------------------------------------------------------
__global__ __launch_bounds__(256)
void bilinear_mfma(const unsigned short* __restrict__ Q,
                   const unsigned short* __restrict__ P1b, const unsigned short* __restrict__ P2b,
                   const unsigned short* __restrict__ D1b, const unsigned short* __restrict__ D2b,
                   unsigned short* __restrict__ part, int n)
{
    __shared__ short act_lds[32 * 128];
    const int tid = threadIdx.x;
    const int lane = tid & 63, wave = tid >> 6;
    const int m = blockIdx.y;
    const int a0 = blockIdx.x * 32;
    const i64 S = (i64)NA * F;
    const unsigned short* M1 = (m < 3) ? P1b : D1b;
    const unsigned short* M2 = (m < 3) ? P2b : D2b;
    const unsigned short* A = Q + (i64)m * S;

    #pragma unroll
    for (int it = 0; it < 2; ++it){
        int ch = tid + it * 256;          // 512 16B-chunks
        int row = ch >> 4, o16 = ch & 15;
        int g = a0 + row;
        uint4 v = make_uint4(0u, 0u, 0u, 0u);
        if (g < n) v = *(const uint4*)(A + (i64)g * F + o16 * 8);
        *(uint4*)((char*)act_lds + swz(row, o16 * 16)) = v;
    }
    __syncthreads();

    f32x4 acc1[2][2], acc2[2][2];
    zero_acc(acc1); zero_acc(acc2);
    gemm_stage(M1, act_lds, acc1, lane, wave);
    gemm_stage(M2, act_lds, acc2, lane, wave);

    const int cl = lane & 15, r4 = (lane >> 4) * 4;
    #pragma unroll
    for (int ntl = 0; ntl < 2; ++ntl){
        int col = wave * 32 + ntl * 16 + cl;
        #pragma unroll
        for (int mt = 0; mt < 2; ++mt){
            #pragma unroll
            for (int j = 0; j < 4; ++j){
                int g = a0 + mt * 16 + r4 + j;
                if (g >= n) continue;
                part[(i64)m * S + (i64)g * F + col] =
                    f2bf(acc1[mt][ntl][j] * acc2[mt][ntl][j]);
            }
        }
    }
}

// ---------------------------------------------------------------------------
// Weight convert f32 -> bf16 (one launch, 10 tensors)
// ---------------------------------------------------------------------------
__global__ __launch_bounds__(256)
void wconv(const float* s0, const float* s1, const float* s2, const float* s3,
           const float* s4, const float* s5, const float* s6, const float* s7,
           const float* s8, const float* s9, unsigned short* __restrict__ dst)
{
    int t = blockIdx.y;
    const float* src; i64 off; int sz;
    if      (t == 0){ src = s0; off = 0;      sz = 65536; }
    else if (t == 1){ src = s1; off = 65536;  sz = 65536; }
    else if (t == 2){ src = s2; off = 131072; sz = 65536; }
    else if (t == 3){ src = s3; off = 196608; sz = 16384; }
    else if (t == 4){ src = s4; off = 212992; sz = 16384; }
    else if (t == 5){ src = s5; off = 229376; sz = 16384; }
    else if (t == 6){ src = s6; off = 245760; sz = 16384; }
    else if (t == 7){ src = s7; off = 262144; sz = 16384; }
    else if (t == 8){ src = s8; off = 278528; sz = 16384; }
    else            { src = s9; off = 294912; sz = 16384; }
    unsigned* d = (unsigned*)(dst + off);
    int pairs = sz >> 1;
    for (int p = blockIdx.x * 256 + threadIdx.x; p < pairs; p += gridDim.x * 256)
        d[p] = pack2(src[2 * p], src[2 * p + 1]);
}

// ---------------------------------------------------------------------------
// Edge prep (unchanged)
// ---------------------------------------------------------------------------
__global__ void prep_count(const float* __restrict__ xyz, const int* __restrict__ nbrs,
                           int* __restrict__ cnt){
    int e = blockIdx.x * 256 + threadIdx.x;
    if (e >= NE) return;
    int i0 = nbrs[2*e], i1 = nbrs[2*e+1];
    float dx = xyz[3*i1]   - xyz[3*i0];
    float dy = xyz[3*i1+1] - xyz[3*i0+1];
    float dz = xyz[3*i1+2] - xyz[3*i0+2];
    float r = sqrtf(dx*dx + dy*dy + dz*dz + 3e-15f);
    if (r < RCUT) atomicAdd(&cnt[i0], 1);
}

__global__ __launch_bounds__(1024)
void scan_kernel(const int* __restrict__ cnt, int* __restrict__ offs){
    __shared__ int part[1024];
    int t = threadIdx.x;
    int loc[5]; int s = 0;
    #pragma unroll
    for (int c = 0; c < 5; ++c){
        int i = t * 5 + c;
        int v = (i < NA) ? cnt[i] : 0;
        loc[c] = s; s += v;
    }
    part[t] = s;
    __syncthreads();
    for (int off = 1; off < 1024; off <<= 1){
        int v = (t >= off) ? part[t - off] : 0;
        __syncthreads();
        part[t] += v;
        __syncthreads();
    }
    int bs = (t == 0) ? 0 : part[t - 1];
    #pragma unroll
    for (int c = 0; c < 5; ++c){
        int i = t * 5 + c;
        if (i <= NA) offs[i] = bs + loc[c];
    }
}

__device__ __forceinline__ void basis16(float r, float g, float fcut, float* b){
    const float C[KB] = {1.f,15.f,105.f,455.f,1365.f,3003.f,5005.f,6435.f,
                         6435.f,5005.f,3003.f,1365.f,455.f,105.f,15.f,1.f};
    float e = __expf(-fmaxf(g, 0.f) * r);
    float one = 1.f - e;
    float ep = 1.f;
    #pragma unroll
    for (int k = 0; k < KB; ++k){ b[k] = C[k] * ep * fcut; ep *= e; }
    float op = 1.f;
    #pragma unroll
    for (int k = KB-1; k >= 0; --k){ b[k] *= op; op *= one; }
}

__global__ void prep_fill(const float* __restrict__ xyz, const int* __restrict__ nbrs,
                          const int* __restrict__ offs, int* __restrict__ fill,
                          const float* __restrict__ gs, const float* __restrict__ gp,
                          const float* __restrict__ gd, float* __restrict__ rec){
    int e = blockIdx.x * 256 + threadIdx.x;
    if (e >= NE) return;
    int i0 = nbrs[2*e], i1 = nbrs[2*e+1];
    float dx = xyz[3*i1]   - xyz[3*i0];
    float dy = xyz[3*i1+1] - xyz[3*i0+1];
    float dz = xyz[3*i1+2] - xyz[3*i0+2];
    float r2 = dx*dx + dy*dy + dz*dz + 3e-15f;
    float r = sqrtf(r2);
    if (r >= RCUT) return;
    int pos = offs[i0] + atomicAdd(&fill[i0], 1);
    float* R = rec + (i64)pos * RECW;
    float ir = 1.f / r;
    R[0] = __int_as_float(i1);
    R[1] = dx * ir; R[2] = dy * ir; R[3] = dz * ir;
    float fcut = __expf(-r2 / ((RCUT - r) * (RCUT + r)));
    float bs[KB], bp[KB], bd[KB];
    basis16(r, gs[0], fcut, bs);
    basis16(r, gp[0], fcut, bp);
    basis16(r, gd[0], fcut, bd);
    unsigned* RW = (unsigned*)(R + 4);
    #pragma unroll
    for (int k = 0; k < 8; ++k) RW[k]      = pack2(bs[2*k], bs[2*k+1]);
    #pragma unroll
    for (int k = 0; k < 8; ++k) RW[8 + k]  = pack2(bp[2*k], bp[2*k+1]);
    #pragma unroll
    for (int k = 0; k < 8; ++k) RW[16 + k] = pack2(bd[2*k], bd[2*k+1]);
}

// ---------------------------------------------------------------------------
// Moment gather (unchanged)
// ---------------------------------------------------------------------------
__global__ __launch_bounds__(256)
void q_gather(const float* __restrict__ rec, const int* __restrict__ offs,
              const float* __restrict__ res,
              const float* __restrict__ Gs, const float* __restrict__ Gp,
              const float* __restrict__ Gd,
              float* __restrict__ inp, unsigned short* __restrict__ Q)
{
    const int n = blockIdx.x;
    const int tid = threadIdx.x;
    const int s = tid >> 7;
    const int f = tid & 127;
    const i64 S = (i64)NA * F;

    float G0[KB], G1[KB], G2[KB];
    #pragma unroll
    for (int q4 = 0; q4 < 4; ++q4){
        *(float4*)&G0[q4*4] = *(const float4*)(Gs + f*KB + q4*4);
        *(float4*)&G1[q4*4] = *(const float4*)(Gp + f*KB + q4*4);
        *(float4*)&G2[q4*4] = *(const float4*)(Gd + f*KB + q4*4);
    }

    float qs = 0.f;
    float qp0=0.f, qp1=0.f, qp2=0.f;
    float qd0=0.f, qd1=0.f, qd2=0.f, qd3=0.f, qd4=0.f;

    __shared__ float recs[16 * RECW];
    __shared__ float red[2][9][128];

    const int e0 = offs[n], e1 = offs[n+1];
    const int cnt_e = e1 - e0;
    const float s3 = 1.7320508075688772f;

    for (int base = 0; base < cnt_e; base += 16){
        int mrec = min(16, cnt_e - base);
        for (int w = tid; w < mrec * RECW; w += 256)
            recs[w] = rec[(i64)(e0 + base) * RECW + w];
        __syncthreads();
        for (int j = s; j < mrec; j += 2){
            const float* R = &recs[j * RECW];
            int i1 = __float_as_int(R[0]);
            float ux = R[1], uy = R[2], uz = R[3];
            const unsigned* bw = (const unsigned*)(R + 4);
            float ds = 0.f, dp = 0.f, dd = 0.f;
            #pragma unroll
            for (int k = 0; k < 8; ++k){
                unsigned w = bw[k];
                ds += G0[2*k] * __uint_as_float(w << 16) + G0[2*k+1] * __uint_as_float(w & 0xffff0000u);
            }
            #pragma unroll
            for (int k = 0; k < 8; ++k){
                unsigned w = bw[8+k];
                dp += G1[2*k] * __uint_as_float(w << 16) + G1[2*k+1] * __uint_as_float(w & 0xffff0000u);
            }
            #pragma unroll
            for (int k = 0; k < 8; ++k){
                unsigned w = bw[16+k];
                dd += G2[2*k] * __uint_as_float(w << 16) + G2[2*k+1] * __uint_as_float(w & 0xffff0000u);
            }
            float a1 = res[S   + (i64)i1*F + f];
            float a2 = res[2*S + (i64)i1*F + f];
            float a3 = res[3*S + (i64)i1*F + f];
            qs += a1 * ds;
            float tp = a2 * dp;
            qp0 += tp * uy; qp1 += tp * uz; qp2 += tp * ux;
            float td = a3 * dd;
            qd0 += td * (s3 * ux * uy);
            qd1 += td * (s3 * uy * uz);
            qd2 += td * (1.5f * uz * uz - 0.5f);
            qd3 += td * (s3 * ux * uz);
            qd4 += td * (0.5f * s3 * (ux*ux - uy*uy));
        }
        __syncthreads();
    }

    red[s][0][f] = qs;
    red[s][1][f] = qp0; red[s][2][f] = qp1; red[s][3][f] = qp2;
    red[s][4][f] = qd0; red[s][5][f] = qd1; red[s][6][f] = qd2;
    red[s][7][f] = qd3; red[s][8][f] = qd4;
    __syncthreads();
    if (s == 0){
        float sums[9];
        #pragma unroll
        for (int i = 0; i < 9; ++i) sums[i] = red[0][i][f] + red[1][i][f];
        inp[(i64)n*F + f] = res[(i64)n*F + f] + sums[0];
        #pragma unroll
        for (int mm = 0; mm < 8; ++mm)
            Q[(i64)mm * S + (i64)n*F + f] = f2bf(sums[1 + mm]);
    }
}

// ---------------------------------------------------------------------------
extern "C" void kernel_launch(void* const* d_in, const int* in_sizes, int n_in,
                              void* d_out, int out_size, void* d_ws, size_t ws_size,
                              hipStream_t stream)
{
    const float* xyz     = (const float*)d_in[0];
    const float* x_tilde = (const float*)d_in[1];
    const int*   nbrs    = (const int*)d_in[2];
    const float* rm_W1 = (const float*)d_in[3],  *rm_b1 = (const float*)d_in[4];
    const float* rm_W2 = (const float*)d_in[5],  *rm_b2 = (const float*)d_in[6];
    const float* rm_W3 = (const float*)d_in[7],  *rm_b3 = (const float*)d_in[8];
    const float* rl_W1 = (const float*)d_in[9],  *rl_b1 = (const float*)d_in[10];
    const float* rl_W2 = (const float*)d_in[11], *rl_b2 = (const float*)d_in[12];
    const float* rl_W3 = (const float*)d_in[13], *rl_b3 = (const float*)d_in[14];
    const float* G_s = (const float*)d_in[15], *G_p = (const float*)d_in[16], *G_d = (const float*)d_in[17];
    const float* P_1 = (const float*)d_in[18], *P_2 = (const float*)d_in[19];
    const float* D_1 = (const float*)d_in[20], *D_2 = (const float*)d_in[21];
    const float* gamma_s = (const float*)d_in[22], *gamma_p = (const float*)d_in[23], *gamma_d = (const float*)d_in[24];
    const float* sw_a = (const float*)d_in[25], *sw_b = (const float*)d_in[26];

    const i64 S = (i64)NA * F;
    float* res  = (float*)d_ws;                      // 4S floats
    float* inp  = res + 4 * S;                       // S floats
    unsigned short* Q = (unsigned short*)(inp + S);  // 8S ushorts
    float* rec  = inp + S + 4 * S;                   // NE*RECW floats (aliased by part)
    unsigned short* part = (unsigned short*)rec;     // 8S ushorts
    int* cnt    = (int*)(rec + (i64)NE * RECW);
    int* fill   = cnt + NA;
    int* offs   = fill + NA;                         // NA+1
    unsigned short* Wb = (unsigned short*)(offs + NA + 8);  // 311296 shorts bf16 weights

    hipMemsetAsync(cnt, 0, 2 * NA * sizeof(int), stream);

    // bf16 weight conversion (one launch, 10 tensors)
    wconv<<<dim3(32, 10), 256, 0, stream>>>(rm_W1, rm_W2, rm_W3, rl_W1, rl_W2, rl_W3,
                                            P_1, P_2, D_1, D_2, Wb);

    const int NT = (NA + 31) / 32;   // 157

    // residual MLP: 4 channels (x -> res[c]), MFMA
    mlp3_mfma<0,1,2,1,1,0><<<dim3(NT, 4), 256, 0, stream>>>(
        x_tilde, (const unsigned short*)nullptr,
        Wb + 0, rm_b1, Wb + 65536, rm_b2, Wb + 131072, rm_b3,
        res, S, sw_a, sw_b, NA);

    // CSR over ACTIVE edges + per-edge records
    prep_count<<<(NE+255)/256, 256, 0, stream>>>(xyz, nbrs, cnt);
    scan_kernel<<<1, 1024, 0, stream>>>(cnt, offs);
    prep_fill<<<(NE+255)/256, 256, 0, stream>>>(xyz, nbrs, offs, fill,
                                                gamma_s, gamma_p, gamma_d, rec);

    // moments + inp = res0 + q_s (rec consumed here)
    q_gather<<<NA, 256, 0, stream>>>(rec, offs, res, G_s, G_p, G_d, inp, Q);

    // bilinear P/D contraction -> part[m] (bf16, aliases rec region), MFMA
    bilinear_mfma<<<dim3(NT, 8), 256, 0, stream>>>(
        Q, Wb + 245760, Wb + 262144, Wb + 278528, Wb + 294912, part, NA);

    // final MLP (inp + sum_m part -> out), MFMA
    mlp3_mfma<3,4,5,1,0,1><<<dim3(NT, 1), 256, 0, stream>>>(
        inp, part,
        Wb + 196608, rl_b1, Wb + 212992, rl_b2, Wb + 229376, rl_b3,
        (float*)d_out, 0, sw_a, sw_b, NA);
}